// Round 8
// baseline (211.263 us; speedup 1.0000x reference)
//
#include <hip/hip_runtime.h>

#define MA 64
#define F 128
#define NF 16
#define HID 512
#define LDUB 144    // ub row stride BYTES (128 fp8 + 16 pad)
#define LDWB 144    // wL row stride bytes (64 bf16 + 8 pad elems)
#define LDT1B 1040  // t1 row stride bytes (512 bf16 + 8 pad elems)
// double-buffer base offsets (bytes)
#define UB0 0
#define UB1 9216
#define WL0 18432
#define WL1 27648

typedef float  float4v __attribute__((ext_vector_type(4)));
typedef short  short8  __attribute__((ext_vector_type(8)));
typedef int    int8v   __attribute__((ext_vector_type(8)));

// pack two fp32 -> (bf16(y)<<16)|bf16(x), round-half-up via +0x8000 then v_perm
static __device__ __forceinline__ unsigned int pack2bf(float x, float y) {
    unsigned int a = __float_as_uint(x) + 0x8000u;
    unsigned int b = __float_as_uint(y) + 0x8000u;
    return __builtin_amdgcn_perm(b, a, 0x07060302u);
}
static __device__ __forceinline__ unsigned short f2bf1(float x) {
    return (unsigned short)((__float_as_uint(x) + 0x8000u) >> 16);
}
// pack 4 fp32 -> 4 fp8 e4m3 (RNE, saturating) in one dword
static __device__ __forceinline__ unsigned int pk4fp8(float a, float b, float c, float d) {
    int p = __builtin_amdgcn_cvt_pk_fp8_f32(a, b, 0, false);
    p = __builtin_amdgcn_cvt_pk_fp8_f32(c, d, p, true);
    return (unsigned int)p;
}

// lgkm-only barrier: LDS producer/consumer sync WITHOUT draining vmcnt, so
// global prefetches (W1 frags / aw2) stay in flight across the rendezvous.
#define LGKM_BAR() do {                                        \
    asm volatile("s_waitcnt lgkmcnt(0)" ::: "memory");         \
    __builtin_amdgcn_s_barrier();                              \
    asm volatile("" ::: "memory");                             \
} while (0)

// ---- Pack W1 as fp8 MX A-frags (16x16x128) of W1^T; W2 as bf16 A-frags
// (16x16x32) of W2^T. Direct gather. (r6 version)
__global__ void pack_frags(const float* __restrict__ W1, const float* __restrict__ W2,
                           unsigned char* __restrict__ w1p, unsigned short* __restrict__ w2p) {
    int gid  = blockIdx.x * 4 + (threadIdx.x >> 6);
    int lane = threadIdx.x & 63;
    int arow = lane & 15;
    int kq   = lane >> 4;
    if (gid < 544) {                           // W1: kt (17 over K=2176, 128 each) x jt (32)
        int kt = gid >> 5, jt = gid & 31;
        const float* base = W1 + (size_t)(kt * 128 + kq * 32) * HID + jt * 16 + arow;
        unsigned int o[8];
        #pragma unroll
        for (int p = 0; p < 8; p++)
            o[p] = pk4fp8(base[(p * 4 + 0) * HID], base[(p * 4 + 1) * HID],
                          base[(p * 4 + 2) * HID], base[(p * 4 + 3) * HID]);
        unsigned char* dst = w1p + ((size_t)gid * 64 + lane) * 32;
        *(uint4*)dst        = (uint4){o[0], o[1], o[2], o[3]};
        *(uint4*)(dst + 16) = (uint4){o[4], o[5], o[6], o[7]};
    } else if (gid < 544 + 128) {              // W2: kt (16 over J=512) x mt (8 over 128)
        int g2 = gid - 544;
        int kt = g2 >> 3, mt = g2 & 7;
        const float* base = W2 + (size_t)(kt * 32 + kq * 8) * F + mt * 16 + arow;
        short8 o;
        #pragma unroll
        for (int j = 0; j < 8; j++) o[j] = (short)f2bf1(base[j * F]);
        *(short8*)(w2p + ((size_t)g2 * 64 + lane) * 8) = o;
    }
}

// ---- Main fused kernel: ONE molecule per block, 1024 threads = 16 waves ----
// PRODUCER/CONSUMER WAVE SPECIALIZATION (r3/r6 failed to overlap the LDS /
// MFMA / VALU pipes because every wave ran the same serial chain; here the
// chains are split by ROLE so the pipes run concurrently by construction):
//  CONSUMERS (waves 0-7, 2/SIMD): GEMM1 only. Wave owns j-tiles ci*4..+3 x
//   all 4 a-tiles (acc[4][4] = 64 AGPR, 16 MX MFMA/interval). W1 frags
//   streamed 2-deep (j0,j1 prefetched across barrier; j2,j3 issued at
//   interval start, ~400cy cover). W1 read EXACTLY ONCE per block (r4/r7
//   lesson: 2x W1 L2 traffic saturates per-XCD L2 and stalls prefetch).
//  PRODUCERS (waves 8-15, 2/SIMD): u-GEMM (1 a-tile x 4 c-tiles, 8 bf16
//   MFMA; each bw read feeds 4 c-slices -> wL reads 64->16KB/interval),
//   exp w_{f+1} (8/thread), all ub/wL writes.
// SEPARATE LOOPS per role -> register live-sets don't interfere (consumer
// ~115, producer ~75; single shared loop would union to >128 and spill=r2).
// Barrier counts identical: syncthreads + LGKM + 17 in-loop + 1 post-loop.
__launch_bounds__(1024, 4)
__global__ void node_conv_mfma(const int* __restrict__ z, const float* __restrict__ rr,
        const float* __restrict__ h, const float* __restrict__ dist,
        const float* __restrict__ wid, const float* __restrict__ b1,
        const float* __restrict__ b2,
        const unsigned char* __restrict__ w1p, const unsigned short* __restrict__ w2p,
        float* __restrict__ out) {
    const int n = blockIdx.x;                  // molecule index
    const int tid = threadIdx.x;
    const int lane = tid & 63;
    const int wave = tid >> 6;                 // 0..15
    const int arow = lane & 15;
    const int quad = lane >> 4;
    const int kgrp = quad * 8;
    const int whi = wave >> 1;                 // GEMM2: c-tile
    const int wlo = wave & 1;                  // GEMM2: a-pair selector
    const bool consumer = wave < 8;            // waves 0,4 | 8,12 etc: 2+2 per SIMD

    __shared__ __attribute__((aligned(16))) unsigned char lds[66560];
    __shared__ float r_lds[MA][5];             // xyz + mask, stride-5

    const int N = gridDim.x;
    const float* hg = h + (size_t)n * MA * F;

    // ---- z / r passthrough + r/mask staging ----
    if (tid < MA) {
        int zi = z[n * MA + tid];
        out[(size_t)n * MA + tid] = (float)zi;
        r_lds[tid][0] = rr[(n * MA + tid) * 3 + 0];
        r_lds[tid][1] = rr[(n * MA + tid) * 3 + 1];
        r_lds[tid][2] = rr[(n * MA + tid) * 3 + 2];
        r_lds[tid][3] = (zi > -1) ? 1.0f : 0.0f;
    }
    if (tid < MA * 3)
        out[(size_t)N * MA + (size_t)n * MA * 3 + tid] = rr[(size_t)n * MA * 3 + tid];

    // ---- stage h -> ub0 (row-major fp8), all 1024 threads ----
    for (int i = tid; i < MA * F / 4; i += 1024) {
        float4 v = ((const float4*)hg)[i];
        int a = i >> 5, c4 = (i & 31) * 4;
        *(unsigned int*)&lds[UB0 + a * LDUB + c4] = pk4fp8(v.x, v.y, v.z, v.w);
    }

    const float4v zf = {0.f, 0.f, 0.f, 0.f};

    if (consumer) {
        // =========================== CONSUMER ===========================
        const int ci = wave;                   // 0..7
        const int jbase = ci * 4;              // 4 j-tiles: jbase..jbase+3

        // seg-0 frags j0,j1: issue before syncthreads (global, rides through)
        int8v p0, p1, p2, p3;
        {
            const unsigned char* pp = w1p + ((size_t)(jbase * 64 + lane)) * 32;
            p0 = *(const int8v*)pp;
            p1 = *(const int8v*)(pp + 2048);
        }
        __syncthreads();                       // r_lds + ub0 visible (barrier #1)
        LGKM_BAR();                            // wL0 written by producers (barrier #2)

        float4v acc[4][4];                     // [jj][at] = 64 AGPRs
        #pragma unroll
        for (int i = 0; i < 4; i++)
            #pragma unroll
            for (int jv = 0; jv < 4; jv++) acc[i][jv] = zf;

        for (int f = 0; f <= NF; f++) {
            const int ubR = (f & 1) ? UB1 : UB0;
            const unsigned char* pseg = w1p + ((size_t)((f * 32 + jbase) * 64 + lane)) * 32;

            // issue this segment's j2,j3 first (cover = 8 MFMAs + bfr reads)
            p2 = *(const int8v*)(pseg + 2 * 2048);
            p3 = *(const int8v*)(pseg + 3 * 2048);

            // half 1: j-tiles jbase+0,1 over all 4 a-tiles
            #pragma unroll
            for (int at = 0; at < 4; at++) {
                int8v bfr = *(const int8v*)&lds[ubR + (at * 16 + arow) * LDUB + quad * 32];
                acc[0][at] = __builtin_amdgcn_mfma_scale_f32_16x16x128_f8f6f4(
                    p0, bfr, acc[0][at], 0, 0, 0, 127, 0, 127);
                acc[1][at] = __builtin_amdgcn_mfma_scale_f32_16x16x128_f8f6f4(
                    p1, bfr, acc[1][at], 0, 0, 0, 127, 0, 127);
            }
            // half 2: j-tiles jbase+2,3 (bfr re-read; keeps regs <=128)
            #pragma unroll
            for (int at = 0; at < 4; at++) {
                int8v bfr = *(const int8v*)&lds[ubR + (at * 16 + arow) * LDUB + quad * 32];
                acc[2][at] = __builtin_amdgcn_mfma_scale_f32_16x16x128_f8f6f4(
                    p2, bfr, acc[2][at], 0, 0, 0, 127, 0, 127);
                acc[3][at] = __builtin_amdgcn_mfma_scale_f32_16x16x128_f8f6f4(
                    p3, bfr, acc[3][at], 0, 0, 0, 127, 0, 127);
            }
            if (f < NF) {                      // prefetch next seg j0,j1 (rides barrier)
                const unsigned char* pN = w1p + ((size_t)(((f + 1) * 32 + jbase) * 64 + lane)) * 32;
                p0 = *(const int8v*)pN;
                p1 = *(const int8v*)(pN + 2048);
            }
            LGKM_BAR();                        // barriers #3..#19
        }

        // t1 = silu(acc + b1) -> LDS (overlays ub/wL; all main-loop reads drained)
        #pragma unroll
        for (int jj = 0; jj < 4; jj++) {
            float4 b1v = *(const float4*)&b1[(jbase + jj) * 16 + quad * 4];
            #pragma unroll
            for (int at = 0; at < 4; at++) {
                float xs[4];
                #pragma unroll
                for (int r = 0; r < 4; r++) {
                    float x = acc[jj][at][r] + ((const float*)&b1v)[r];
                    xs[r] = x / (1.0f + __expf(-x));
                }
                uint2 pv = { pack2bf(xs[0], xs[1]), pack2bf(xs[2], xs[3]) };
                *(uint2*)&lds[(at * 16 + arow) * LDT1B + ((jbase + jj) * 16 + quad * 4) * 2] = pv;
            }
        }
    } else {
        // =========================== PRODUCER ===========================
        const int pi = wave - 8;               // 0..7
        const int uat = pi & 3;                // u-GEMM a-tile
        const int uc0 = (pi >> 2) * 4;         // first of 4 c-tiles
        const int pt  = tid - 512;             // 0..511
        const int wa  = pt >> 3;               // exp: a-atom 0..63
        const int wb0 = (pt & 7) * 8;          // exp: first of 8 b-atoms

        // hT A-fragments (bf16) for 4 c-slices: global-only, before syncthreads
        short8 ah2[4][2];
        #pragma unroll
        for (int cc = 0; cc < 4; cc++) {
            int c = (uc0 + cc) * 16 + arow;
            #pragma unroll
            for (int ks2 = 0; ks2 < 2; ks2++)
                #pragma unroll
                for (int j = 0; j < 8; j++)
                    ah2[cc][ks2][j] = (short)f2bf1(hg[(size_t)(ks2 * 32 + kgrp + j) * F + c]);
        }
        __syncthreads();                       // r_lds visible (barrier #1)

        // masked distances: 8 (a,b) pairs per thread (unique coverage of 64x64)
        float dpre[8];
        {
            float ax = r_lds[wa][0], ay = r_lds[wa][1], az = r_lds[wa][2];
            float am = r_lds[wa][3];
            #pragma unroll
            for (int j = 0; j < 8; j++) {
                float dx = ax - r_lds[wb0 + j][0];
                float dy = ay - r_lds[wb0 + j][1];
                float dz = az - r_lds[wb0 + j][2];
                float d = sqrtf(dx * dx + dy * dy + dz * dz + 1e-12f);
                float mm = am * r_lds[wb0 + j][3];
                dpre[j] = d + (1.0f - mm) * 1e4f;
            }
        }
        // w filter 0 -> wL0
        {
            float mu = dist[0];
            float isg = 1.0f / wid[0];
            float e[8];
            #pragma unroll
            for (int j = 0; j < 8; j++) {
                float t = dpre[j] - mu;
                e[j] = 5.0f * __expf(-t * t * isg);
            }
            uint4 wp = { pack2bf(e[0], e[1]), pack2bf(e[2], e[3]),
                         pack2bf(e[4], e[5]), pack2bf(e[6], e[7]) };
            *(uint4*)&lds[WL0 + wa * LDWB + wb0 * 2] = wp;
        }
        LGKM_BAR();                            // wL0 visible (barrier #2)

        for (int f = 0; f <= NF; f++) {
            const int sel = f & 1;
            const int ubW = sel ? UB0 : UB1;
            const int wlR = sel ? WL1 : WL0;
            const int wlW = sel ? WL0 : WL1;

            if (f < NF) {
                // u-GEMM: u_f^T = hT @ w_f; ONE bw pair feeds all 4 c-slices
                short8 bw0 = *(const short8*)&lds[wlR + (uat * 16 + arow) * LDWB + (0 * 32 + kgrp) * 2];
                short8 bw1 = *(const short8*)&lds[wlR + (uat * 16 + arow) * LDWB + (1 * 32 + kgrp) * 2];
                #pragma unroll
                for (int cc = 0; cc < 4; cc++) {
                    float4v ud = zf;
                    ud = __builtin_amdgcn_mfma_f32_16x16x32_bf16(ah2[cc][0], bw0, ud, 0, 0, 0);
                    ud = __builtin_amdgcn_mfma_f32_16x16x32_bf16(ah2[cc][1], bw1, ud, 0, 0, 0);
                    unsigned int up = pk4fp8(ud[0], ud[1], ud[2], ud[3]);
                    *(unsigned int*)&lds[ubW + (uat * 16 + arow) * LDUB + (uc0 + cc) * 16 + quad * 4] = up;
                }
                if (f <= NF - 2) {             // exp w_{f+1} -> write buffer
                    float mu = dist[f + 1];
                    float isg = 1.0f / wid[f + 1];
                    float e[8];
                    #pragma unroll
                    for (int j = 0; j < 8; j++) {
                        float t = dpre[j] - mu;
                        e[j] = 5.0f * __expf(-t * t * isg);
                    }
                    uint4 wp = { pack2bf(e[0], e[1]), pack2bf(e[2], e[3]),
                                 pack2bf(e[4], e[5]), pack2bf(e[6], e[7]) };
                    *(uint4*)&lds[wlW + wa * LDWB + wb0 * 2] = wp;
                }
            }
            LGKM_BAR();                        // barriers #3..#19
        }
    }

    LGKM_BAR();                                // t1 fully visible (barrier #20, both paths)

    // ---- GEMM2 (bf16, ALL 16 waves): out = h + 0.1*mask*(silu(t1) @ W2 + b2) ----
    float4v g2[2] = { zf, zf };                // this wave: c-tile whi, a-pair wlo

    short8 awA = *(const short8*)(w2p + ((size_t)(whi) * 64 + lane) * 8);   // ks=0
    #pragma unroll
    for (int ks2 = 0; ks2 < 8; ks2++) {
        const int k1 = 2 * ks2 + 1;
        short8 awB = *(const short8*)(w2p + ((size_t)(k1 * 8 + whi) * 64 + lane) * 8);
        #pragma unroll
        for (int j = 0; j < 2; j++) {
            short8 bt = *(const short8*)&lds[((wlo * 2 + j) * 16 + arow) * LDT1B + ((2 * ks2) * 32 + kgrp) * 2];
            g2[j] = __builtin_amdgcn_mfma_f32_16x16x32_bf16(awA, bt, g2[j], 0, 0, 0);
        }
        const int k2 = (ks2 < 7) ? 2 * ks2 + 2 : 0;   // harmless re-read on last iter
        awA = *(const short8*)(w2p + ((size_t)(k2 * 8 + whi) * 64 + lane) * 8);
        #pragma unroll
        for (int j = 0; j < 2; j++) {
            short8 bt = *(const short8*)&lds[((wlo * 2 + j) * 16 + arow) * LDT1B + ((2 * ks2 + 1) * 32 + kgrp) * 2];
            g2[j] = __builtin_amdgcn_mfma_f32_16x16x32_bf16(awB, bt, g2[j], 0, 0, 0);
        }
    }

    // D[m=c][n=a]: a = (wlo*2+j)*16+arow, c = whi*16 + quad*4 + r
    float* outh = out + (size_t)N * MA * 4 + (size_t)n * MA * F;
    const int c0 = whi * 16 + quad * 4;
    float4 b2v = *(const float4*)&b2[c0];
    #pragma unroll
    for (int j = 0; j < 2; j++) {
        int a = (wlo * 2 + j) * 16 + arow;
        float m = r_lds[a][3] * 0.1f;
        float4 hv = *(const float4*)&hg[a * F + c0];
        float4 res;
        res.x = hv.x + (g2[j][0] + b2v.x) * m;
        res.y = hv.y + (g2[j][1] + b2v.y) * m;
        res.z = hv.z + (g2[j][2] + b2v.z) * m;
        res.w = hv.w + (g2[j][3] + b2v.w) * m;
        *(float4*)&outh[(size_t)a * F + c0] = res;
    }
}

extern "C" void kernel_launch(void* const* d_in, const int* in_sizes, int n_in,
                              void* d_out, int out_size, void* d_ws, size_t ws_size,
                              hipStream_t stream) {
    const int*   z    = (const int*)d_in[0];
    const float* rr   = (const float*)d_in[1];
    const float* h    = (const float*)d_in[2];
    const float* dist = (const float*)d_in[3];
    const float* wid  = (const float*)d_in[4];
    const float* W1   = (const float*)d_in[5];
    const float* b1   = (const float*)d_in[6];
    const float* W2   = (const float*)d_in[7];
    const float* b2   = (const float*)d_in[8];
    float* out = (float*)d_out;

    int Nmol = in_sizes[0] / MA;                           // 512 molecules

    unsigned char*  w1p = (unsigned char*)d_ws;            // 544*64*32 = 1,114,112 B
    unsigned short* w2p = (unsigned short*)(w1p + (size_t)544 * 64 * 32);  // 128 KB bf16

    pack_frags<<<168, 256, 0, stream>>>(W1, W2, w1p, w2p);
    node_conv_mfma<<<Nmol, 1024, 0, stream>>>(z, rr, h, dist, wid, b1, b2, w1p, w2p, out);
}

// Round 10
// 146.543 us; speedup vs baseline: 1.4416x; 1.4416x over previous
//
#include <hip/hip_runtime.h>

#define MA 64
#define F 128
#define NF 16
#define HID 512
#define LDUB 144    // ub row stride BYTES (128 fp8 + 16 pad)
#define LDWB 144    // wL row stride bytes (64 bf16 + 8 pad elems)
#define LDT1B 1040  // t1 row stride bytes (512 bf16 + 8 pad elems)
// double-buffered DOUBLE-WIDE buffers: each ub buffer holds 2 u-tiles (the
// two K=128 segments of one interval); each wL buffer holds 2 filters.
#define UBA 0
#define UBB 18432
#define WLA 36864
#define WLB 55296
#define UBT 9216    // tile stride inside a ub buffer
#define WLT 9216    // filter-slot stride inside a wL buffer

typedef float  float4v __attribute__((ext_vector_type(4)));
typedef short  short8  __attribute__((ext_vector_type(8)));
typedef int    int8v   __attribute__((ext_vector_type(8)));

// pack two fp32 -> (bf16(y)<<16)|bf16(x), round-half-up via +0x8000 then v_perm
static __device__ __forceinline__ unsigned int pack2bf(float x, float y) {
    unsigned int a = __float_as_uint(x) + 0x8000u;
    unsigned int b = __float_as_uint(y) + 0x8000u;
    return __builtin_amdgcn_perm(b, a, 0x07060302u);
}
static __device__ __forceinline__ unsigned short f2bf1(float x) {
    return (unsigned short)((__float_as_uint(x) + 0x8000u) >> 16);
}
// pack 4 fp32 -> 4 fp8 e4m3 (RNE, saturating) in one dword
static __device__ __forceinline__ unsigned int pk4fp8(float a, float b, float c, float d) {
    int p = __builtin_amdgcn_cvt_pk_fp8_f32(a, b, 0, false);
    p = __builtin_amdgcn_cvt_pk_fp8_f32(c, d, p, true);
    return (unsigned int)p;
}

// lgkm-only barrier: LDS producer/consumer sync WITHOUT draining vmcnt, so
// global prefetches (W1 frags / aw2) stay in flight across the rendezvous.
#define LGKM_BAR() do {                                        \
    asm volatile("s_waitcnt lgkmcnt(0)" ::: "memory");         \
    __builtin_amdgcn_s_barrier();                              \
    asm volatile("" ::: "memory");                             \
} while (0)

// ---- Pack W1 as fp8 MX A-frags (16x16x128) of W1^T; W2 as bf16 A-frags
// (16x16x32) of W2^T. Direct gather. (unchanged)
__global__ void pack_frags(const float* __restrict__ W1, const float* __restrict__ W2,
                           unsigned char* __restrict__ w1p, unsigned short* __restrict__ w2p) {
    int gid  = blockIdx.x * 4 + (threadIdx.x >> 6);
    int lane = threadIdx.x & 63;
    int arow = lane & 15;
    int kq   = lane >> 4;
    if (gid < 544) {                           // W1: kt (17 over K=2176, 128 each) x jt (32)
        int kt = gid >> 5, jt = gid & 31;
        const float* base = W1 + (size_t)(kt * 128 + kq * 32) * HID + jt * 16 + arow;
        unsigned int o[8];
        #pragma unroll
        for (int p = 0; p < 8; p++)
            o[p] = pk4fp8(base[(p * 4 + 0) * HID], base[(p * 4 + 1) * HID],
                          base[(p * 4 + 2) * HID], base[(p * 4 + 3) * HID]);
        unsigned char* dst = w1p + ((size_t)gid * 64 + lane) * 32;
        *(uint4*)dst        = (uint4){o[0], o[1], o[2], o[3]};
        *(uint4*)(dst + 16) = (uint4){o[4], o[5], o[6], o[7]};
    } else if (gid < 544 + 128) {              // W2: kt (16 over J=512) x mt (8 over 128)
        int g2 = gid - 544;
        int kt = g2 >> 3, mt = g2 & 7;
        const float* base = W2 + (size_t)(kt * 32 + kq * 8) * F + mt * 16 + arow;
        short8 o;
        #pragma unroll
        for (int j = 0; j < 8; j++) o[j] = (short)f2bf1(base[j * F]);
        *(short8*)(w2p + ((size_t)g2 * 64 + lane) * 8) = o;
    }
}

// ---- Main fused kernel: ONE molecule per block, 1024 threads = 16 waves ----
// r3 structure (best, 70us) with TWO K-SEGMENTS PER BARRIER INTERVAL: the
// elimination rounds (r4-r8) showed the binder is the FIXED per-interval cost
// (16-wave barrier skew + lgkm drain + head-of-interval ds_read->MFMA
// latency), paid 17x. Pairing segments pays it 9x: main loop = 8 fat
// intervals + 1 final segment; barriers 19 -> 12. Per-segment work, tiling
// and partitions are r3's unchanged (W1 read exactly once; frag pair for
// seg 2i+1 loads under seg 2i's MFMAs; pair for seg 2i+2 rides the barrier).
__launch_bounds__(1024, 4)
__global__ void node_conv_mfma(const int* __restrict__ z, const float* __restrict__ rr,
        const float* __restrict__ h, const float* __restrict__ dist,
        const float* __restrict__ wid, const float* __restrict__ b1,
        const float* __restrict__ b2,
        const unsigned char* __restrict__ w1p, const unsigned short* __restrict__ w2p,
        float* __restrict__ out) {
    const int n = blockIdx.x;                  // molecule index
    const int tid = threadIdx.x;
    const int lane = tid & 63;
    const int wave = tid >> 6;                 // 0..15
    const int arow = lane & 15;
    const int quad = lane >> 4;
    const int kgrp = quad * 8;
    const int whi = wave >> 1;                 // u-GEMM/GEMM2: c-slice
    const int wlo = wave & 1;                  // u-GEMM/GEMM2: a-pair selector

    __shared__ __attribute__((aligned(16))) unsigned char lds[73728];
    __shared__ float r_lds[MA][5];             // xyz + mask, stride-5

    const int N = gridDim.x;
    const float* hg = h + (size_t)n * MA * F;

    // ---- z / r passthrough + r/mask staging ----
    if (tid < MA) {
        int zi = z[n * MA + tid];
        out[(size_t)n * MA + tid] = (float)zi;
        r_lds[tid][0] = rr[(n * MA + tid) * 3 + 0];
        r_lds[tid][1] = rr[(n * MA + tid) * 3 + 1];
        r_lds[tid][2] = rr[(n * MA + tid) * 3 + 2];
        r_lds[tid][3] = (zi > -1) ? 1.0f : 0.0f;
    }
    if (tid < MA * 3)
        out[(size_t)N * MA + (size_t)n * MA * 3 + tid] = rr[(size_t)n * MA * 3 + tid];

    // ---- stage h -> UBA tile0 (row-major fp8): segment 0's B-operand ----
    for (int i = tid; i < MA * F / 4; i += 1024) {
        float4 v = ((const float4*)hg)[i];
        int a = i >> 5, c4 = (i & 31) * 4;
        *(unsigned int*)&lds[UBA + a * LDUB + c4] = pk4fp8(v.x, v.y, v.z, v.w);
    }
    // ---- hT A-fragments in registers (bf16): lane holds h[b][c], c = whi*16+arow ----
    short8 ah[2];
    {
        int c = whi * 16 + arow;
        #pragma unroll
        for (int ks2 = 0; ks2 < 2; ks2++)
            #pragma unroll
            for (int j = 0; j < 8; j++)
                ah[ks2][j] = (short)f2bf1(hg[(size_t)(ks2 * 32 + kgrp + j) * F + c]);
    }
    // ---- seg-0 A-frag pair: issue before syncthreads, rides everything ----
    int8v p0, p1, q0, q1;
    {
        const unsigned char* pp = w1p + ((size_t)((wave * 2) * 64 + lane)) * 32;
        p0 = *(const int8v*)pp;
        p1 = *(const int8v*)(pp + 2048);
    }
    __syncthreads();                           // r_lds + staged h visible (full drain, once)

    // ---- per-thread pairwise distances (4 pairs/thread), mask folded in ----
    const int wa = tid >> 4;                   // 0..63
    const int wb0 = (tid & 15) * 4;            // 0,4,..,60
    float dpre[4];
    {
        float ax = r_lds[wa][0], ay = r_lds[wa][1], az = r_lds[wa][2];
        float am = r_lds[wa][3];
        #pragma unroll
        for (int j = 0; j < 4; j++) {
            float dx = ax - r_lds[wb0 + j][0];
            float dy = ay - r_lds[wb0 + j][1];
            float dz = az - r_lds[wb0 + j][2];
            float d = sqrtf(dx * dx + dy * dy + dz * dz + 1e-12f);
            float mm = am * r_lds[wb0 + j][3];
            dpre[j] = d + (1.0f - mm) * 1e4f;
        }
    }

    // ---- phase helpers ----
    auto EXPW = [&](int fidx, int wlOff) {     // exp filter fidx -> wL slot
        float mu = dist[fidx];
        float isg = 1.0f / wid[fidx];
        float e[4];
        #pragma unroll
        for (int j = 0; j < 4; j++) {
            float t = dpre[j] - mu;
            e[j] = 5.0f * __expf(-t * t * isg);
        }
        uint2 wp = { pack2bf(e[0], e[1]), pack2bf(e[2], e[3]) };
        *(uint2*)&lds[wlOff + wa * LDWB + wb0 * 2] = wp;
    };
    const float4v zf = {0.f, 0.f, 0.f, 0.f};
    auto UG = [&](int wlOff, int ubOff) {      // u = h^T w (bf16); fp8 store
        float4v ud0 = zf, ud1 = zf;
        #pragma unroll
        for (int ks2 = 0; ks2 < 2; ks2++) {
            short8 bw0 = *(const short8*)&lds[wlOff + ((wlo * 2 + 0) * 16 + arow) * LDWB + (ks2 * 32 + kgrp) * 2];
            ud0 = __builtin_amdgcn_mfma_f32_16x16x32_bf16(ah[ks2], bw0, ud0, 0, 0, 0);
            short8 bw1 = *(const short8*)&lds[wlOff + ((wlo * 2 + 1) * 16 + arow) * LDWB + (ks2 * 32 + kgrp) * 2];
            ud1 = __builtin_amdgcn_mfma_f32_16x16x32_bf16(ah[ks2], bw1, ud1, 0, 0, 0);
        }
        unsigned int u0 = pk4fp8(ud0[0], ud0[1], ud0[2], ud0[3]);
        unsigned int u1 = pk4fp8(ud1[0], ud1[1], ud1[2], ud1[3]);
        *(unsigned int*)&lds[ubOff + ((wlo * 2 + 0) * 16 + arow) * LDUB + whi * 16 + quad * 4] = u0;
        *(unsigned int*)&lds[ubOff + ((wlo * 2 + 1) * 16 + arow) * LDUB + whi * 16 + quad * 4] = u1;
    };

    // ---- prologue: w0 -> WLB s0 (scratch); w1,w2 -> WLA; then u0 -> UBA tile1
    EXPW(0, WLB);
    EXPW(1, WLA);
    EXPW(2, WLA + WLT);
    LGKM_BAR();                                // w0/w1/w2 + staged h visible
    UG(WLB, UBA + UBT);                        // u_0 = h @ w_0 -> UBA tile1
    LGKM_BAR();                                // u_0 visible; seg-0 frag loads done riding

    float4v acc[2][4];                         // [mt = j-tile][at = a-tile] = 32 AGPRs
    #pragma unroll
    for (int i = 0; i < 2; i++)
        #pragma unroll
        for (int jv = 0; jv < 4; jv++) acc[i][jv] = zf;

    // ---- main loop: 8 fat intervals, each = segs {2i, 2i+1}, ONE barrier ----
    for (int i = 0; i < 8; i++) {
        const int sel = i & 1;
        const int ubR = sel ? UBB : UBA;
        const int ubW = sel ? UBA : UBB;
        const int wlR = sel ? WLB : WLA;
        const int wlW = sel ? WLA : WLB;

        // issue seg 2i+1 frag pair now (completes under seg-2i MFMAs)
        {
            const unsigned char* pq = w1p + ((size_t)(((2 * i + 1) * 32 + wave * 2) * 64 + lane)) * 32;
            q0 = *(const int8v*)pq;
            q1 = *(const int8v*)(pq + 2048);
        }
        // GEMM1 seg 2i (tile0): j-tiles wave*2+{0,1} x 4 a-tiles
        #pragma unroll
        for (int at = 0; at < 4; at++) {
            int8v bfr = *(const int8v*)&lds[ubR + (at * 16 + arow) * LDUB + quad * 32];
            acc[0][at] = __builtin_amdgcn_mfma_scale_f32_16x16x128_f8f6f4(
                p0, bfr, acc[0][at], 0, 0, 0, 127, 0, 127);
            acc[1][at] = __builtin_amdgcn_mfma_scale_f32_16x16x128_f8f6f4(
                p1, bfr, acc[1][at], 0, 0, 0, 127, 0, 127);
        }
        // GEMM1 seg 2i+1 (tile1)
        #pragma unroll
        for (int at = 0; at < 4; at++) {
            int8v bfr = *(const int8v*)&lds[ubR + UBT + (at * 16 + arow) * LDUB + quad * 32];
            acc[0][at] = __builtin_amdgcn_mfma_scale_f32_16x16x128_f8f6f4(
                q0, bfr, acc[0][at], 0, 0, 0, 127, 0, 127);
            acc[1][at] = __builtin_amdgcn_mfma_scale_f32_16x16x128_f8f6f4(
                q1, bfr, acc[1][at], 0, 0, 0, 127, 0, 127);
        }
        // prefetch seg 2i+2 frag pair (rides the barrier on vmcnt)
        {
            const unsigned char* pp = w1p + ((size_t)(((2 * i + 2) * 32 + wave * 2) * 64 + lane)) * 32;
            p0 = *(const int8v*)pp;
            p1 = *(const int8v*)(pp + 2048);
        }

        // u-GEMM: u_{2i+1} -> ubW tile0; u_{2i+2} -> ubW tile1 (if filter exists)
        UG(wlR, ubW);                          // filter 2i+1 (<=15 for i<=7)
        if (2 * i + 2 <= NF - 1) UG(wlR + WLT, ubW + UBT);
        // exp: w_{2i+3} -> wlW s0; w_{2i+4} -> wlW s1
        if (2 * i + 3 <= NF - 1) EXPW(2 * i + 3, wlW);
        if (2 * i + 4 <= NF - 1) EXPW(2 * i + 4, wlW + WLT);

        LGKM_BAR();                            // interval rendezvous (8 total)
    }

    // ---- final segment 16: reads UBA tile0 = u_15 (written in interval 7) ----
    #pragma unroll
    for (int at = 0; at < 4; at++) {
        int8v bfr = *(const int8v*)&lds[UBA + (at * 16 + arow) * LDUB + quad * 32];
        acc[0][at] = __builtin_amdgcn_mfma_scale_f32_16x16x128_f8f6f4(
            p0, bfr, acc[0][at], 0, 0, 0, 127, 0, 127);
        acc[1][at] = __builtin_amdgcn_mfma_scale_f32_16x16x128_f8f6f4(
            p1, bfr, acc[1][at], 0, 0, 0, 127, 0, 127);
    }
    LGKM_BAR();                                // all ub/wL reads drained (t1 overlays)

    // ---- GEMM2 (bf16): out = h + 0.1*mask*(silu(t1) @ W2 + b2) ----
    // Full t1 (64 x 512) staged once (overlays ub/wL). W2 A-frags streamed
    // 2-deep from L2-resident w2p.
    float4 b1v[2];
    #pragma unroll
    for (int mt = 0; mt < 2; mt++)
        b1v[mt] = *(const float4*)&b1[wave * 32 + mt * 16 + quad * 4];

    #pragma unroll
    for (int mt = 0; mt < 2; mt++) {
        #pragma unroll
        for (int at = 0; at < 4; at++) {
            float xs[4];
            #pragma unroll
            for (int r = 0; r < 4; r++) {
                float x = acc[mt][at][r] + ((const float*)&b1v[mt])[r];
                xs[r] = x / (1.0f + __expf(-x));
            }
            uint2 pv = { pack2bf(xs[0], xs[1]), pack2bf(xs[2], xs[3]) };
            *(uint2*)&lds[(at * 16 + arow) * LDT1B + (wave * 32 + mt * 16 + quad * 4) * 2] = pv;
        }
    }
    LGKM_BAR();                                // full t1 visible; aw2 stream rides through

    float4v g2[2] = { zf, zf };                // this wave: c-tile whi, a-pair wlo

    short8 awA = *(const short8*)(w2p + ((size_t)(whi) * 64 + lane) * 8);   // ks=0
    #pragma unroll
    for (int ks2 = 0; ks2 < 8; ks2++) {
        const int k1 = 2 * ks2 + 1;
        short8 awB = *(const short8*)(w2p + ((size_t)(k1 * 8 + whi) * 64 + lane) * 8);
        #pragma unroll
        for (int j = 0; j < 2; j++) {
            short8 bt = *(const short8*)&lds[((wlo * 2 + j) * 16 + arow) * LDT1B + ((2 * ks2) * 32 + kgrp) * 2];
            g2[j] = __builtin_amdgcn_mfma_f32_16x16x32_bf16(awA, bt, g2[j], 0, 0, 0);
        }
        const int k2 = (ks2 < 7) ? 2 * ks2 + 2 : 0;   // harmless re-read on last iter
        awA = *(const short8*)(w2p + ((size_t)(k2 * 8 + whi) * 64 + lane) * 8);
        #pragma unroll
        for (int j = 0; j < 2; j++) {
            short8 bt = *(const short8*)&lds[((wlo * 2 + j) * 16 + arow) * LDT1B + ((2 * ks2 + 1) * 32 + kgrp) * 2];
            g2[j] = __builtin_amdgcn_mfma_f32_16x16x32_bf16(awB, bt, g2[j], 0, 0, 0);
        }
    }

    // D[m=c][n=a]: a = (wlo*2+j)*16+arow, c = whi*16 + quad*4 + r
    float* outh = out + (size_t)N * MA * 4 + (size_t)n * MA * F;
    const int c0 = whi * 16 + quad * 4;
    float4 b2v = *(const float4*)&b2[c0];
    #pragma unroll
    for (int j = 0; j < 2; j++) {
        int a = (wlo * 2 + j) * 16 + arow;
        float m = r_lds[a][3] * 0.1f;
        float4 hv = *(const float4*)&hg[a * F + c0];
        float4 res;
        res.x = hv.x + (g2[j][0] + b2v.x) * m;
        res.y = hv.y + (g2[j][1] + b2v.y) * m;
        res.z = hv.z + (g2[j][2] + b2v.z) * m;
        res.w = hv.w + (g2[j][3] + b2v.w) * m;
        *(float4*)&outh[(size_t)a * F + c0] = res;
    }
}

extern "C" void kernel_launch(void* const* d_in, const int* in_sizes, int n_in,
                              void* d_out, int out_size, void* d_ws, size_t ws_size,
                              hipStream_t stream) {
    const int*   z    = (const int*)d_in[0];
    const float* rr   = (const float*)d_in[1];
    const float* h    = (const float*)d_in[2];
    const float* dist = (const float*)d_in[3];
    const float* wid  = (const float*)d_in[4];
    const float* W1   = (const float*)d_in[5];
    const float* b1   = (const float*)d_in[6];
    const float* W2   = (const float*)d_in[7];
    const float* b2   = (const float*)d_in[8];
    float* out = (float*)d_out;

    int Nmol = in_sizes[0] / MA;                           // 512 molecules

    unsigned char*  w1p = (unsigned char*)d_ws;            // 544*64*32 = 1,114,112 B
    unsigned short* w2p = (unsigned short*)(w1p + (size_t)544 * 64 * 32);  // 128 KB bf16

    pack_frags<<<168, 256, 0, stream>>>(W1, W2, w1p, w2p);
    node_conv_mfma<<<Nmol, 1024, 0, stream>>>(z, rr, h, dist, wid, b1, b2, w1p, w2p, out);
}